// Round 3
// baseline (739.541 us; speedup 1.0000x reference)
//
#include <hip/hip_runtime.h>
#include <math.h>

#define BATCH 512
#define ITERS 1000

typedef float f32x2 __attribute__((ext_vector_type(2)));
typedef float f32x4 __attribute__((ext_vector_type(4)));

__device__ __forceinline__ float rdlane(float v, int l) {
  return __int_as_float(__builtin_amdgcn_readlane(__float_as_int(v), l));
}
__device__ __forceinline__ f32x2 fma2(f32x2 a, f32x2 b, f32x2 c) {
#if __has_builtin(__builtin_elementwise_fma)
  return __builtin_elementwise_fma(a, b, c);
#else
  f32x2 r; r.x = fmaf(a.x, b.x, c.x); r.y = fmaf(a.y, b.y, c.y); return r;
#endif
}

// Register-resident Gauss-Jordan on [A|I] (32x64); lane holds column `lane`
// of augmented row r in g[r]. Broadcasts via v_readlane (uniform SGPR).
#define GJ32_REG(g)                                            \
  _Pragma("unroll")                                            \
  for (int k = 0; k < 32; ++k) {                               \
    float inv = 1.0f / rdlane(g[k], k);                        \
    g[k] *= inv;                                               \
    _Pragma("unroll")                                          \
    for (int ii = 0; ii < 32; ++ii) {                          \
      if (ii == k) continue;                                   \
      float f = rdlane(g[ii], k);                              \
      g[ii] = fmaf(-f, g[k], g[ii]);                           \
    }                                                          \
  }

// One wave per batch row. Every block redundantly computes the setup
// (P^-1, D, lambda_max via power iteration on D^2, Hinv) in registers,
// then runs 1000 iterations with the primal GEMV fused (one iteration
// behind, broadcasts via LDS ring so the DS pipe overlaps matvec VALU).
__global__ __launch_bounds__(64, 1)
void fused_kernel(const float* __restrict__ q,
                  const float* __restrict__ bmat,
                  const float* __restrict__ P,
                  const float* __restrict__ H,
                  float* __restrict__ Xs,
                  float* __restrict__ out2) {
  __shared__ __align__(16) float lds[2112 + 128];
  float* Hlp = lds;          // phase B: 64 x 33 (H staging)
  float* HTp = lds;          // phase B: 32 x 66 (Hinv transpose), reuses region
  float* xb  = lds + 2112;   // main loop: 2 x 64 ring of (x2 - b)

  const int row = blockIdx.x, lane = threadIdx.x;
  const int i = lane & 31, h = lane >> 5;

  const float bl = bmat[row * 64 + lane];

  // ---- load H row `lane`, stage to LDS for transpose ----
  float hreg[32];
  {
    const f32x4* hp = (const f32x4*)(H + lane * 32);
    #pragma unroll
    for (int j4 = 0; j4 < 8; ++j4) {
      f32x4 t = hp[j4];
      hreg[4*j4+0] = t.x; hreg[4*j4+1] = t.y; hreg[4*j4+2] = t.z; hreg[4*j4+3] = t.w;
    }
    #pragma unroll
    for (int j = 0; j < 32; ++j) Hlp[lane * 33 + j] = hreg[j];
  }
  __syncthreads();   // single wave: cheap

  // ---- phase B: Hinv = (H^T H)^-1 H^T, delivered as per-lane half-rows ----
  f32x2 hv2[16];     // lane (h,i): Hinv[i][32h + 2t .. +1]
  {
    float htc[64];   // htc[m] = H[m][lane&31]
    #pragma unroll
    for (int m = 0; m < 64; ++m) htc[m] = Hlp[m * 33 + i];

    float gB[32];
    #pragma unroll
    for (int r = 0; r < 32; ++r) {
      float a0 = 0.f, a1 = 0.f;
      #pragma unroll
      for (int m = 0; m < 64; m += 2) {
        a0 = fmaf(rdlane(hreg[r], m),     htc[m],     a0);
        a1 = fmaf(rdlane(hreg[r], m + 1), htc[m + 1], a1);
      }
      float hth = a0 + a1;   // (H^T H)[r][lane&31]
      gB[r] = (lane < 32) ? hth : (((lane - 32) == r) ? 1.0f : 0.0f);
    }
    GJ32_REG(gB)
    __syncthreads();          // htc fully read; region about to be re-used as HT
    #pragma unroll
    for (int r = 0; r < 32; ++r) {        // Hinv[r][lane]
      float a0 = 0.f, a1 = 0.f;
      #pragma unroll
      for (int c = 0; c < 32; c += 2) {
        a0 = fmaf(rdlane(gB[r], 32 + c),     hreg[c],     a0);
        a1 = fmaf(rdlane(gB[r], 32 + c + 1), hreg[c + 1], a1);
      }
      HTp[r * 66 + lane] = a0 + a1;
    }
    __syncthreads();
    #pragma unroll
    for (int t = 0; t < 16; ++t)
      hv2[t] = *(const f32x2*)&HTp[i * 66 + 32 * h + 2 * t];
  }

  // ---- phase A: P^-1, P^-1 H^T, D, lambda_max, s ----
  float pht[32], dcol[64], acc;
  {
    float g[32];
    #pragma unroll
    for (int r = 0; r < 32; ++r) {
      float pv = P[r * 32 + i];
      g[r] = (lane < 32) ? pv : (((lane - 32) == r) ? 1.0f : 0.0f);
    }
    GJ32_REG(g)
    #pragma unroll
    for (int r = 0; r < 32; ++r) {        // (P^-1 H^T)[r][lane]
      float a0 = 0.f, a1 = 0.f;
      #pragma unroll
      for (int j = 0; j < 32; j += 2) {
        a0 = fmaf(rdlane(g[r], 32 + j),     hreg[j],     a0);
        a1 = fmaf(rdlane(g[r], 32 + j + 1), hreg[j + 1], a1);
      }
      pht[r] = a0 + a1;
    }
  }
  {
    const float* qp = q + row * 32;       // wave-uniform -> s_loads
    float a0 = 0.f, a1 = 0.f;
    #pragma unroll
    for (int r = 0; r < 32; r += 2) {
      a0 = fmaf(qp[r],     pht[r],     a0);
      a1 = fmaf(qp[r + 1], pht[r + 1], a1);
    }
    acc = a0 + a1;                        // (H P^-1 q)[lane]
  }
  #pragma unroll
  for (int r = 0; r < 64; ++r) {          // D[r][lane] (symmetric)
    float a0 = 0.f, a1 = 0.f;
    #pragma unroll
    for (int j = 0; j < 32; j += 2) {
      a0 = fmaf(rdlane(hreg[j],     r), pht[j],     a0);
      a1 = fmaf(rdlane(hreg[j + 1], r), pht[j + 1], a1);
    }
    dcol[r] = a0 + a1;
  }
  float s;
  {
    float ecol[64];                       // E = D^2
    #pragma unroll
    for (int r = 0; r < 64; ++r) {
      float a0 = 0.f, a1 = 0.f;
      #pragma unroll
      for (int c = 0; c < 64; c += 2) {
        a0 = fmaf(rdlane(dcol[r], c),     dcol[c],     a0);
        a1 = fmaf(rdlane(dcol[r], c + 1), dcol[c + 1], a1);
      }
      ecol[r] = a0 + a1;
    }
    float v = 1.0f + 0.017f * (float)lane;
    #pragma unroll 1
    for (int t = 0; t < 112; ++t) {
      float a0 = 0.f, a1 = 0.f, a2 = 0.f, a3 = 0.f;
      #pragma unroll
      for (int c = 0; c < 64; c += 4) {
        a0 = fmaf(ecol[c+0], rdlane(v, c+0), a0);
        a1 = fmaf(ecol[c+1], rdlane(v, c+1), a1);
        a2 = fmaf(ecol[c+2], rdlane(v, c+2), a2);
        a3 = fmaf(ecol[c+3], rdlane(v, c+3), a3);
      }
      v = (a0 + a1) + (a2 + a3);
      if ((t & 7) == 7) {
        float n2 = v * v;
        #pragma unroll
        for (int m = 1; m < 64; m <<= 1) n2 += __shfl_xor(n2, m);
        v *= 1.0f / sqrtf(n2);
      }
    }
    float a0 = 0.f, a1 = 0.f, a2 = 0.f, a3 = 0.f;    // Rayleigh with D
    #pragma unroll
    for (int c = 0; c < 64; c += 4) {
      a0 = fmaf(dcol[c+0], rdlane(v, c+0), a0);
      a1 = fmaf(dcol[c+1], rdlane(v, c+1), a1);
      a2 = fmaf(dcol[c+2], rdlane(v, c+2), a2);
      a3 = fmaf(dcol[c+3], rdlane(v, c+3), a3);
    }
    float w = (a0 + a1) + (a2 + a3);
    float num = w * v, den = v * v;
    #pragma unroll
    for (int m = 1; m < 64; m <<= 1) {
      num += __shfl_xor(num, m);
      den += __shfl_xor(den, m);
    }
    s = den / num;                        // s = 1 / lambda_max(D)
  }
  const float mu = s * (acc - bl);
  #pragma unroll
  for (int r = 0; r < 64; ++r) dcol[r] *= s;   // dcol := row `lane` of s*D

  // ---- main loop: matvec + fused (one-behind) primal ----
  float* Xp = Xs + (size_t)row * (ITERS + 1) * 128;
  float* ob = out2 + (size_t)row * (ITERS + 1) * 32;
  Xp[lane] = 0.f;                         // X0 = 0
  Xp[64 + lane] = 0.f;
  xb[lane] = -bl;                         // slot 0 = (x2_0 - b)

  float x1 = 0.f, x2 = 0.f;
  #pragma unroll 1
  for (int k = 1; k <= ITERS; ++k) {
    // issue primal loads for k-1 early (DS pipe overlaps matvec VALU)
    const f32x4* tp = (const f32x4*)(xb + ((k - 1) & 1) * 64 + h * 32);
    f32x4 t0 = tp[0], t1 = tp[1], t2 = tp[2], t3 = tp[3];
    f32x4 t4 = tp[4], t5 = tp[5], t6 = tp[6], t7 = tp[7];

    float a0 = 0.f, a1 = 0.f, a2 = 0.f, a3 = 0.f;
    #pragma unroll
    for (int j = 0; j < 64; j += 4) {
      a0 = fmaf(dcol[j+0], rdlane(x1, j+0), a0);
      a1 = fmaf(dcol[j+1], rdlane(x1, j+1), a1);
      a2 = fmaf(dcol[j+2], rdlane(x1, j+2), a2);
      a3 = fmaf(dcol[j+3], rdlane(x1, j+3), a3);
    }
    float x1n = ((a0 + a1) + (a2 + a3)) + fmaf(s, x2, mu);
    float x2n = fmaxf(fmaf(-2.0f, x1n, x1 + x2), 0.f);
    Xp += 128;
    Xp[lane] = x1n;
    Xp[64 + lane] = x2n;
    xb[(k & 1) * 64 + lane] = x2n - bl;   // ring slot for iteration k

    // primal for k-1: p[i] = sum_j Hinv[i][j] * (x2_{k-1}[j] - b[j])
    f32x2 pa; pa.x = 0.f; pa.y = 0.f;
    f32x2 pb = pa;
    pa = fma2(hv2[0],  t0.xy, pa);  pb = fma2(hv2[1],  t0.zw, pb);
    pa = fma2(hv2[2],  t1.xy, pa);  pb = fma2(hv2[3],  t1.zw, pb);
    pa = fma2(hv2[4],  t2.xy, pa);  pb = fma2(hv2[5],  t2.zw, pb);
    pa = fma2(hv2[6],  t3.xy, pa);  pb = fma2(hv2[7],  t3.zw, pb);
    pa = fma2(hv2[8],  t4.xy, pa);  pb = fma2(hv2[9],  t4.zw, pb);
    pa = fma2(hv2[10], t5.xy, pa);  pb = fma2(hv2[11], t5.zw, pb);
    pa = fma2(hv2[12], t6.xy, pa);  pb = fma2(hv2[13], t6.zw, pb);
    pa = fma2(hv2[14], t7.xy, pa);  pb = fma2(hv2[15], t7.zw, pb);
    float p = (pa.x + pa.y) + (pb.x + pb.y);
    p += __shfl_xor(p, 32);               // combine j-halves
    if (h == 0) ob[(size_t)(k - 1) * 32 + i] = p;

    x1 = x1n; x2 = x2n;
  }
  // final primal (k = ITERS)
  {
    const f32x4* tp = (const f32x4*)(xb + (ITERS & 1) * 64 + h * 32);
    f32x2 pa; pa.x = 0.f; pa.y = 0.f;
    f32x2 pb = pa;
    #pragma unroll
    for (int r4 = 0; r4 < 8; ++r4) {
      f32x4 t = tp[r4];
      pa = fma2(hv2[2*r4],     t.xy, pa);
      pb = fma2(hv2[2*r4 + 1], t.zw, pb);
    }
    float p = (pa.x + pa.y) + (pb.x + pb.y);
    p += __shfl_xor(p, 32);
    if (h == 0) ob[(size_t)ITERS * 32 + i] = p;
  }
}

extern "C" void kernel_launch(void* const* d_in, const int* in_sizes, int n_in,
                              void* d_out, int out_size, void* d_ws, size_t ws_size,
                              hipStream_t stream) {
  (void)in_sizes; (void)n_in; (void)out_size; (void)d_ws; (void)ws_size;
  const float* q = (const float*)d_in[0];
  const float* b = (const float*)d_in[1];
  const float* P = (const float*)d_in[2];
  const float* H = (const float*)d_in[3];
  float* Xs = (float*)d_out;
  float* out2 = Xs + (size_t)BATCH * (ITERS + 1) * 128;

  fused_kernel<<<BATCH, 64, 0, stream>>>(q, b, P, H, Xs, out2);
}

// Round 6
// 615.571 us; speedup vs baseline: 1.2014x; 1.2014x over previous
//
#include <hip/hip_runtime.h>
#include <math.h>

#define BATCH 512
#define ITERS 1000
#define PHASES 125   // 8 iterations per phase

typedef float f32x2 __attribute__((ext_vector_type(2)));
typedef float f32x4 __attribute__((ext_vector_type(4)));

// NOTE: readlane requires a WAVE-UNIFORM lane index (v_readlane_b32 takes the
// index from an SGPR). All rdlane() calls below use compile-time constants.
// For divergent indices use __shfl (ds_bpermute). Violating this was the
// round-4/5 bug (corrupted primal[:,0,:]).
__device__ __forceinline__ float rdlane(float v, int l) {
  return __int_as_float(__builtin_amdgcn_readlane(__float_as_int(v), l));
}
__device__ __forceinline__ f32x2 fma2(f32x2 a, f32x2 b, f32x2 c) {
#if __has_builtin(__builtin_elementwise_fma)
  return __builtin_elementwise_fma(a, b, c);
#else
  f32x2 r; r.x = fmaf(a.x, b.x, c.x); r.y = fmaf(a.y, b.y, c.y); return r;
#endif
}

// Register-resident Gauss-Jordan on [A|I] (32x64); lane holds column `lane`
// of augmented row r in g[r]. Broadcasts via v_readlane (uniform SGPR).
#define GJ32_REG(g)                                            \
  _Pragma("unroll")                                            \
  for (int k = 0; k < 32; ++k) {                               \
    float inv = 1.0f / rdlane(g[k], k);                        \
    g[k] *= inv;                                               \
    _Pragma("unroll")                                          \
    for (int ii = 0; ii < 32; ++ii) {                          \
      if (ii == k) continue;                                   \
      float f = rdlane(g[ii], k);                              \
      g[ii] = fmaf(-f, g[k], g[ii]);                           \
    }                                                          \
  }

// One block per batch row; wave 0 = iterator (recurrence + Xs stores + LDS
// ring producer), wave 1 = primal GEMV consumer. Ring is double-buffered
// 8-slot; one __syncthreads per 8 iterations.
__global__ __launch_bounds__(128, 1)
void fused_kernel(const float* __restrict__ q,
                  const float* __restrict__ bmat,
                  const float* __restrict__ P,
                  const float* __restrict__ H,
                  float* __restrict__ Xs,
                  float* __restrict__ out2) {
  __shared__ __align__(16) float stage[2112];     // wave 1: Hl 64x33 -> HT 32x66
  __shared__ __align__(16) float ring[2][8][64];  // [buf][slot][component]

  const int tid = threadIdx.x;
  const int wv = tid >> 6;          // 0 = iterator, 1 = primal
  const int lane = tid & 63;
  const int row = blockIdx.x;
  const int i = lane & 31, h = lane >> 5;

  // ---- H row `lane` (both waves need it) ----
  float hreg[32];
  {
    const f32x4* hp = (const f32x4*)(H + lane * 32);
    #pragma unroll
    for (int j4 = 0; j4 < 8; ++j4) {
      f32x4 t = hp[j4];
      hreg[4*j4+0] = t.x; hreg[4*j4+1] = t.y; hreg[4*j4+2] = t.z; hreg[4*j4+3] = t.w;
    }
  }
  const float bl = bmat[row * 64 + lane];

  float dcol[64]; float s = 0.f, mu = 0.f;        // iterator state
  f32x2 hv2[16];                                  // primal state
  float* Xp = Xs + (size_t)row * (ITERS + 1) * 128;
  float* ob = out2 + (size_t)row * (ITERS + 1) * 32;

  // ---------- wave-1 Hinv transpose, block-wide barriers (B1..B3) ----------
  if (wv == 1) {
    #pragma unroll
    for (int j = 0; j < 32; ++j) stage[lane * 33 + j] = hreg[j];
  }
  __syncthreads();                                // B1
  float gB[32];
  if (wv == 1) {
    float htc[64];                                // htc[m] = H[m][i]
    #pragma unroll
    for (int m = 0; m < 64; ++m) htc[m] = stage[m * 33 + i];
    #pragma unroll
    for (int r = 0; r < 32; ++r) {
      float a0 = 0.f, a1 = 0.f;
      #pragma unroll
      for (int m = 0; m < 64; m += 2) {
        a0 = fmaf(rdlane(hreg[r], m),     htc[m],     a0);
        a1 = fmaf(rdlane(hreg[r], m + 1), htc[m + 1], a1);
      }
      float hth = a0 + a1;                        // (H^T H)[r][i]
      gB[r] = (lane < 32) ? hth : (((lane - 32) == r) ? 1.0f : 0.0f);
    }
    GJ32_REG(gB)
  }
  __syncthreads();                                // B2 (htc reads done; region reused)
  if (wv == 1) {
    #pragma unroll
    for (int r = 0; r < 32; ++r) {                // Hinv[r][lane] -> transposed staging
      float a0 = 0.f, a1 = 0.f;
      #pragma unroll
      for (int c = 0; c < 32; c += 2) {
        a0 = fmaf(rdlane(gB[r], 32 + c),     hreg[c],     a0);
        a1 = fmaf(rdlane(gB[r], 32 + c + 1), hreg[c + 1], a1);
      }
      stage[r * 66 + lane] = a0 + a1;
    }
  }
  __syncthreads();                                // B3
  if (wv == 1) {
    #pragma unroll
    for (int t = 0; t < 16; ++t)                  // lane (h,i): Hinv[i][32h+2t..+1]
      hv2[t] = *(const f32x2*)&stage[i * 66 + 32 * h + 2 * t];
  }

  if (wv == 0) {
    // ---------- phase A (registers only): P^-1, P^-1 H^T, D, lambda_max ----------
    float pht[32], acc;
    {
      float g[32];
      #pragma unroll
      for (int r = 0; r < 32; ++r) {
        float pv = P[r * 32 + i];
        g[r] = (lane < 32) ? pv : (((lane - 32) == r) ? 1.0f : 0.0f);
      }
      GJ32_REG(g)
      #pragma unroll
      for (int r = 0; r < 32; ++r) {      // (P^-1 H^T)[r][lane]
        float a0 = 0.f, a1 = 0.f;
        #pragma unroll
        for (int j = 0; j < 32; j += 2) {
          a0 = fmaf(rdlane(g[r], 32 + j),     hreg[j],     a0);
          a1 = fmaf(rdlane(g[r], 32 + j + 1), hreg[j + 1], a1);
        }
        pht[r] = a0 + a1;
      }
    }
    {
      const float* qp = q + row * 32;     // wave-uniform -> s_loads
      float a0 = 0.f, a1 = 0.f;
      #pragma unroll
      for (int r = 0; r < 32; r += 2) {
        a0 = fmaf(qp[r],     pht[r],     a0);
        a1 = fmaf(qp[r + 1], pht[r + 1], a1);
      }
      acc = a0 + a1;                      // (H P^-1 q)[lane]
    }
    #pragma unroll
    for (int r = 0; r < 64; ++r) {        // D[r][lane] (symmetric)
      float a0 = 0.f, a1 = 0.f;
      #pragma unroll
      for (int j = 0; j < 32; j += 2) {
        a0 = fmaf(rdlane(hreg[j],     r), pht[j],     a0);
        a1 = fmaf(rdlane(hreg[j + 1], r), pht[j + 1], a1);
      }
      dcol[r] = a0 + a1;
    }
    {
      float ecol[64];                     // E = D^2 (squares convergence rate)
      #pragma unroll
      for (int r = 0; r < 64; ++r) {
        float a0 = 0.f, a1 = 0.f;
        #pragma unroll
        for (int c = 0; c < 64; c += 2) {
          a0 = fmaf(rdlane(dcol[r], c),     dcol[c],     a0);
          a1 = fmaf(rdlane(dcol[r], c + 1), dcol[c + 1], a1);
        }
        ecol[r] = a0 + a1;
      }
      float v = 1.0f + 0.017f * (float)lane;
      #pragma unroll 1
      for (int t = 0; t < 112; ++t) {
        float a0 = 0.f, a1 = 0.f, a2 = 0.f, a3 = 0.f;
        #pragma unroll
        for (int c = 0; c < 64; c += 4) {
          a0 = fmaf(ecol[c+0], rdlane(v, c+0), a0);
          a1 = fmaf(ecol[c+1], rdlane(v, c+1), a1);
          a2 = fmaf(ecol[c+2], rdlane(v, c+2), a2);
          a3 = fmaf(ecol[c+3], rdlane(v, c+3), a3);
        }
        v = (a0 + a1) + (a2 + a3);
        if ((t & 7) == 7) {
          float n2 = v * v;
          #pragma unroll
          for (int m = 1; m < 64; m <<= 1) n2 += __shfl_xor(n2, m);
          v *= 1.0f / sqrtf(n2);
        }
      }
      float a0 = 0.f, a1 = 0.f, a2 = 0.f, a3 = 0.f;  // Rayleigh with D
      #pragma unroll
      for (int c = 0; c < 64; c += 4) {
        a0 = fmaf(dcol[c+0], rdlane(v, c+0), a0);
        a1 = fmaf(dcol[c+1], rdlane(v, c+1), a1);
        a2 = fmaf(dcol[c+2], rdlane(v, c+2), a2);
        a3 = fmaf(dcol[c+3], rdlane(v, c+3), a3);
      }
      float w = (a0 + a1) + (a2 + a3);
      float num = w * v, den = v * v;
      #pragma unroll
      for (int m = 1; m < 64; m <<= 1) {
        num += __shfl_xor(num, m);
        den += __shfl_xor(den, m);
      }
      s = den / num;                      // s = 1 / lambda_max(D)
    }
    mu = s * (acc - bl);
    #pragma unroll
    for (int r = 0; r < 64; ++r) dcol[r] *= s;   // row `lane` of s*D
    Xp[lane] = 0.f;                       // X0 = 0
    Xp[64 + lane] = 0.f;
  }

  // ---------- main loop: 125 phases x 8 iterations ----------
  float x1 = 0.f, x2 = 0.f;
  #pragma unroll 1
  for (int p = 0; p < PHASES; ++p) {
    if (wv == 0) {
      float* rb = &ring[p & 1][0][0];
      #pragma unroll
      for (int u = 0; u < 8; ++u) {
        float a0 = 0.f, a1 = 0.f, a2 = 0.f, a3 = 0.f;
        #pragma unroll
        for (int j = 0; j < 64; j += 4) {
          a0 = fmaf(dcol[j+0], rdlane(x1, j+0), a0);
          a1 = fmaf(dcol[j+1], rdlane(x1, j+1), a1);
          a2 = fmaf(dcol[j+2], rdlane(x1, j+2), a2);
          a3 = fmaf(dcol[j+3], rdlane(x1, j+3), a3);
        }
        float x1n = ((a0 + a1) + (a2 + a3)) + fmaf(s, x2, mu);
        float x2n = fmaxf(fmaf(-2.0f, x1n, x1 + x2), 0.f);
        Xp += 128;
        Xp[lane] = x1n;
        Xp[64 + lane] = x2n;
        rb[u * 64 + lane] = x2n - bl;     // ring slot for this k
        x1 = x1n; x2 = x2n;
      }
    } else {
      if (p == 0) {
        // k = 0: t_j = -b[j]. Source lane 32h+4t+c is DIVERGENT (h varies per
        // lane) -> must use __shfl (ds_bpermute), NOT readlane (round-4/5 bug).
        f32x2 pa = {0.f, 0.f}, pb = {0.f, 0.f};
        #pragma unroll
        for (int t = 0; t < 8; ++t) {
          f32x2 ta, tb;
          ta.x = -__shfl(bl, 32*h + 4*t + 0, 64);
          ta.y = -__shfl(bl, 32*h + 4*t + 1, 64);
          tb.x = -__shfl(bl, 32*h + 4*t + 2, 64);
          tb.y = -__shfl(bl, 32*h + 4*t + 3, 64);
          pa = fma2(hv2[2*t],     ta, pa);
          pb = fma2(hv2[2*t + 1], tb, pb);
        }
        float pr = (pa.x + pa.y) + (pb.x + pb.y);
        pr += __shfl_xor(pr, 32);
        if (h == 0) ob[i] = pr;
      } else {
        const float* rbuf = &ring[(p - 1) & 1][0][0];
        #pragma unroll
        for (int u = 0; u < 8; ++u) {
          const int k = 8 * (p - 1) + 1 + u;
          const f32x4* tp = (const f32x4*)(rbuf + u * 64 + h * 32);
          f32x2 pa = {0.f, 0.f}, pb = {0.f, 0.f};
          #pragma unroll
          for (int t = 0; t < 8; ++t) {
            f32x4 tv = tp[t];
            pa = fma2(hv2[2*t],     tv.xy, pa);
            pb = fma2(hv2[2*t + 1], tv.zw, pb);
          }
          float pr = (pa.x + pa.y) + (pb.x + pb.y);
          pr += __shfl_xor(pr, 32);
          if (h == 0) ob[(size_t)k * 32 + i] = pr;
        }
      }
    }
    __syncthreads();                      // both waves, every phase: counts match
  }

  if (wv == 1) {
    // tail: phase 124 data (buffer 0), k = 993..1000
    const float* rbuf = &ring[0][0][0];
    #pragma unroll
    for (int u = 0; u < 8; ++u) {
      const int k = 993 + u;
      const f32x4* tp = (const f32x4*)(rbuf + u * 64 + h * 32);
      f32x2 pa = {0.f, 0.f}, pb = {0.f, 0.f};
      #pragma unroll
      for (int t = 0; t < 8; ++t) {
        f32x4 tv = tp[t];
        pa = fma2(hv2[2*t],     tv.xy, pa);
        pb = fma2(hv2[2*t + 1], tv.zw, pb);
      }
      float pr = (pa.x + pa.y) + (pb.x + pb.y);
      pr += __shfl_xor(pr, 32);
      if (h == 0) ob[(size_t)k * 32 + i] = pr;
    }
  }
}

extern "C" void kernel_launch(void* const* d_in, const int* in_sizes, int n_in,
                              void* d_out, int out_size, void* d_ws, size_t ws_size,
                              hipStream_t stream) {
  (void)in_sizes; (void)n_in; (void)out_size; (void)d_ws; (void)ws_size;
  const float* q = (const float*)d_in[0];
  const float* b = (const float*)d_in[1];
  const float* P = (const float*)d_in[2];
  const float* H = (const float*)d_in[3];
  float* Xs = (float*)d_out;
  float* out2 = Xs + (size_t)BATCH * (ITERS + 1) * 128;

  fused_kernel<<<BATCH, 128, 0, stream>>>(q, b, P, H, Xs, out2);
}

// Round 7
// 611.925 us; speedup vs baseline: 1.2085x; 1.0060x over previous
//
#include <hip/hip_runtime.h>
#include <math.h>

#define BATCH 512
#define ITERS 1000
#define PLEN 25      // iterations per phase
#define PHASES 40    // producer phase p covers k = 25p+1 .. 25p+25

typedef float f32x2 __attribute__((ext_vector_type(2)));
typedef float f32x4 __attribute__((ext_vector_type(4)));

// readlane requires a WAVE-UNIFORM lane index (compile-time constants below).
// For divergent indices use __shfl (round-4/5 bug).
__device__ __forceinline__ float rdlane(float v, int l) {
  return __int_as_float(__builtin_amdgcn_readlane(__float_as_int(v), l));
}
__device__ __forceinline__ f32x2 fma2(f32x2 a, f32x2 b, f32x2 c) {
#if __has_builtin(__builtin_elementwise_fma)
  return __builtin_elementwise_fma(a, b, c);
#else
  f32x2 r; r.x = fmaf(a.x, b.x, c.x); r.y = fmaf(a.y, b.y, c.y); return r;
#endif
}

// Register-resident Gauss-Jordan on [A|I] (32x64); lane holds column `lane`.
#define GJ32_REG(g)                                            \
  _Pragma("unroll")                                            \
  for (int k = 0; k < 32; ++k) {                               \
    float inv = 1.0f / rdlane(g[k], k);                        \
    g[k] *= inv;                                               \
    _Pragma("unroll")                                          \
    for (int ii = 0; ii < 32; ++ii) {                          \
      if (ii == k) continue;                                   \
      float f = rdlane(g[ii], k);                              \
      g[ii] = fmaf(-f, g[k], g[ii]);                           \
    }                                                          \
  }

// wave 0 = iterator (pure VALU + 2 ring ds_writes/iter; NO global stores,
// so its barrier drain is lgkmcnt-only). wave 1 = consumer: Xs stores,
// primal GEMV + store. Double-buffered 25-slot ring, 40 barriers total.
__global__ __launch_bounds__(128, 1)
void fused_kernel(const float* __restrict__ q,
                  const float* __restrict__ bmat,
                  const float* __restrict__ P,
                  const float* __restrict__ H,
                  float* __restrict__ Xs,
                  float* __restrict__ out2) {
  __shared__ __align__(16) float stage[2112];        // wave 1: Hl 64x33 -> HT 32x66
  __shared__ __align__(16) float X1R[2][PLEN][64];   // ring: x1
  __shared__ __align__(16) float X2R[2][PLEN][64];   // ring: x2 - b

  const int tid = threadIdx.x;
  const int wv = tid >> 6;          // 0 = iterator, 1 = consumer
  const int lane = tid & 63;
  const int row = blockIdx.x;
  const int i = lane & 31, h = lane >> 5;

  // ---- H row `lane` (both waves need it) ----
  float hreg[32];
  {
    const f32x4* hp = (const f32x4*)(H + lane * 32);
    #pragma unroll
    for (int j4 = 0; j4 < 8; ++j4) {
      f32x4 t = hp[j4];
      hreg[4*j4+0] = t.x; hreg[4*j4+1] = t.y; hreg[4*j4+2] = t.z; hreg[4*j4+3] = t.w;
    }
  }
  const float bl = bmat[row * 64 + lane];

  float dcol[64]; float s = 0.f, mu = 0.f;        // iterator state
  f32x2 hv2[16];                                  // consumer state
  float* Xp = Xs + (size_t)row * (ITERS + 1) * 128;
  float* ob = out2 + (size_t)row * (ITERS + 1) * 32;

  // ---------- wave-1 Hinv transpose (block-wide barriers B1..B3) ----------
  if (wv == 1) {
    #pragma unroll
    for (int j = 0; j < 32; ++j) stage[lane * 33 + j] = hreg[j];
  }
  __syncthreads();                                // B1
  float gB[32];
  if (wv == 1) {
    float htc[64];                                // htc[m] = H[m][i]
    #pragma unroll
    for (int m = 0; m < 64; ++m) htc[m] = stage[m * 33 + i];
    #pragma unroll
    for (int r = 0; r < 32; ++r) {
      float a0 = 0.f, a1 = 0.f;
      #pragma unroll
      for (int m = 0; m < 64; m += 2) {
        a0 = fmaf(rdlane(hreg[r], m),     htc[m],     a0);
        a1 = fmaf(rdlane(hreg[r], m + 1), htc[m + 1], a1);
      }
      float hth = a0 + a1;                        // (H^T H)[r][i]
      gB[r] = (lane < 32) ? hth : (((lane - 32) == r) ? 1.0f : 0.0f);
    }
    GJ32_REG(gB)
  }
  __syncthreads();                                // B2
  if (wv == 1) {
    #pragma unroll
    for (int r = 0; r < 32; ++r) {                // Hinv[r][lane] -> staging
      float a0 = 0.f, a1 = 0.f;
      #pragma unroll
      for (int c = 0; c < 32; c += 2) {
        a0 = fmaf(rdlane(gB[r], 32 + c),     hreg[c],     a0);
        a1 = fmaf(rdlane(gB[r], 32 + c + 1), hreg[c + 1], a1);
      }
      stage[r * 66 + lane] = a0 + a1;
    }
  }
  __syncthreads();                                // B3
  if (wv == 1) {
    #pragma unroll
    for (int t = 0; t < 16; ++t)                  // lane (h,i): Hinv[i][32h+2t..+1]
      hv2[t] = *(const f32x2*)&stage[i * 66 + 32 * h + 2 * t];
  }

  if (wv == 0) {
    // ---------- setup (registers only): P^-1, P^-1 H^T, D, lambda_max ----------
    float pht[32], acc;
    {
      float g[32];
      #pragma unroll
      for (int r = 0; r < 32; ++r) {
        float pv = P[r * 32 + i];
        g[r] = (lane < 32) ? pv : (((lane - 32) == r) ? 1.0f : 0.0f);
      }
      GJ32_REG(g)
      #pragma unroll
      for (int r = 0; r < 32; ++r) {      // (P^-1 H^T)[r][lane]
        float a0 = 0.f, a1 = 0.f;
        #pragma unroll
        for (int j = 0; j < 32; j += 2) {
          a0 = fmaf(rdlane(g[r], 32 + j),     hreg[j],     a0);
          a1 = fmaf(rdlane(g[r], 32 + j + 1), hreg[j + 1], a1);
        }
        pht[r] = a0 + a1;
      }
    }
    {
      const float* qp = q + row * 32;     // wave-uniform -> s_loads
      float a0 = 0.f, a1 = 0.f;
      #pragma unroll
      for (int r = 0; r < 32; r += 2) {
        a0 = fmaf(qp[r],     pht[r],     a0);
        a1 = fmaf(qp[r + 1], pht[r + 1], a1);
      }
      acc = a0 + a1;                      // (H P^-1 q)[lane]
    }
    #pragma unroll
    for (int r = 0; r < 64; ++r) {        // D[r][lane] (symmetric)
      float a0 = 0.f, a1 = 0.f;
      #pragma unroll
      for (int j = 0; j < 32; j += 2) {
        a0 = fmaf(rdlane(hreg[j],     r), pht[j],     a0);
        a1 = fmaf(rdlane(hreg[j + 1], r), pht[j + 1], a1);
      }
      dcol[r] = a0 + a1;
    }
    {
      float ecol[64];                     // E = D^2 (squares convergence rate)
      #pragma unroll
      for (int r = 0; r < 64; ++r) {
        float a0 = 0.f, a1 = 0.f;
        #pragma unroll
        for (int c = 0; c < 64; c += 2) {
          a0 = fmaf(rdlane(dcol[r], c),     dcol[c],     a0);
          a1 = fmaf(rdlane(dcol[r], c + 1), dcol[c + 1], a1);
        }
        ecol[r] = a0 + a1;
      }
      float v = 1.0f + 0.017f * (float)lane;
      #pragma unroll 1
      for (int t = 0; t < 112; ++t) {
        float a0 = 0.f, a1 = 0.f, a2 = 0.f, a3 = 0.f;
        #pragma unroll
        for (int c = 0; c < 64; c += 4) {
          a0 = fmaf(ecol[c+0], rdlane(v, c+0), a0);
          a1 = fmaf(ecol[c+1], rdlane(v, c+1), a1);
          a2 = fmaf(ecol[c+2], rdlane(v, c+2), a2);
          a3 = fmaf(ecol[c+3], rdlane(v, c+3), a3);
        }
        v = (a0 + a1) + (a2 + a3);
        if ((t & 7) == 7) {
          float n2 = v * v;
          #pragma unroll
          for (int m = 1; m < 64; m <<= 1) n2 += __shfl_xor(n2, m);
          v *= 1.0f / sqrtf(n2);
        }
      }
      float a0 = 0.f, a1 = 0.f, a2 = 0.f, a3 = 0.f;  // Rayleigh with D
      #pragma unroll
      for (int c = 0; c < 64; c += 4) {
        a0 = fmaf(dcol[c+0], rdlane(v, c+0), a0);
        a1 = fmaf(dcol[c+1], rdlane(v, c+1), a1);
        a2 = fmaf(dcol[c+2], rdlane(v, c+2), a2);
        a3 = fmaf(dcol[c+3], rdlane(v, c+3), a3);
      }
      float w = (a0 + a1) + (a2 + a3);
      float num = w * v, den = v * v;
      #pragma unroll
      for (int m = 1; m < 64; m <<= 1) {
        num += __shfl_xor(num, m);
        den += __shfl_xor(den, m);
      }
      s = den / num;                      // s = 1 / lambda_max(D)
    }
    mu = s * (acc - bl);
    #pragma unroll
    for (int r = 0; r < 64; ++r) dcol[r] *= s;   // row `lane` of s*D
  }

  // ---------- main loop: 40 phases x 25 iterations ----------
  float x1 = 0.f, x2 = 0.f;
  #pragma unroll 1
  for (int p = 0; p < PHASES; ++p) {
    if (wv == 0) {
      float* rx1 = &X1R[p & 1][0][0];
      float* rx2 = &X2R[p & 1][0][0];
      #pragma unroll 1
      for (int u = 0; u < PLEN; ++u) {
        float a0 = 0.f, a1 = 0.f, a2 = 0.f, a3 = 0.f;
        // batch 8 readlanes ahead of their FMAs (bury SGPR-write->read hazard)
        #pragma unroll
        for (int j8 = 0; j8 < 64; j8 += 8) {
          float b0 = rdlane(x1, j8+0), b1 = rdlane(x1, j8+1);
          float b2 = rdlane(x1, j8+2), b3 = rdlane(x1, j8+3);
          float b4 = rdlane(x1, j8+4), b5 = rdlane(x1, j8+5);
          float b6 = rdlane(x1, j8+6), b7 = rdlane(x1, j8+7);
          a0 = fmaf(dcol[j8+0], b0, a0);
          a1 = fmaf(dcol[j8+1], b1, a1);
          a2 = fmaf(dcol[j8+2], b2, a2);
          a3 = fmaf(dcol[j8+3], b3, a3);
          a0 = fmaf(dcol[j8+4], b4, a0);
          a1 = fmaf(dcol[j8+5], b5, a1);
          a2 = fmaf(dcol[j8+6], b6, a2);
          a3 = fmaf(dcol[j8+7], b7, a3);
        }
        float x1n = ((a0 + a1) + (a2 + a3)) + fmaf(s, x2, mu);
        float x2n = fmaxf(fmaf(-2.0f, x1n, x1 + x2), 0.f);
        rx1[u * 64 + lane] = x1n;
        rx2[u * 64 + lane] = x2n - bl;
        x1 = x1n; x2 = x2n;
      }
    } else {
      if (p == 0) {
        // k = 0: X0 = 0 stores + primal_0 = Hinv @ (-b)
        Xp[lane] = 0.f;
        Xp[64 + lane] = 0.f;
        f32x2 pa = {0.f, 0.f}, pb = {0.f, 0.f};
        #pragma unroll
        for (int t = 0; t < 8; ++t) {
          f32x2 ta, tb;
          ta.x = -__shfl(bl, 32*h + 4*t + 0, 64);
          ta.y = -__shfl(bl, 32*h + 4*t + 1, 64);
          tb.x = -__shfl(bl, 32*h + 4*t + 2, 64);
          tb.y = -__shfl(bl, 32*h + 4*t + 3, 64);
          pa = fma2(hv2[2*t],     ta, pa);
          pb = fma2(hv2[2*t + 1], tb, pb);
        }
        float pr = (pa.x + pa.y) + (pb.x + pb.y);
        pr += __shfl_xor(pr, 32);
        if (h == 0) ob[i] = pr;
      } else {
        const float* rx1 = &X1R[(p - 1) & 1][0][0];
        const float* rx2 = &X2R[(p - 1) & 1][0][0];
        const int k0 = PLEN * (p - 1) + 1;
        float* Xk = Xp + (size_t)k0 * 128;
        float* obk = ob + (size_t)k0 * 32;
        #pragma unroll 1
        for (int u = 0; u < PLEN; ++u) {
          float x1v = rx1[u * 64 + lane];
          float x2mb = rx2[u * 64 + lane];
          Xk[u * 128 + lane] = x1v;
          Xk[u * 128 + 64 + lane] = x2mb + bl;
          const f32x4* tp = (const f32x4*)(rx2 + u * 64 + h * 32);
          f32x2 pa = {0.f, 0.f}, pb = {0.f, 0.f};
          #pragma unroll
          for (int t = 0; t < 8; ++t) {
            f32x4 tv = tp[t];
            pa = fma2(hv2[2*t],     tv.xy, pa);
            pb = fma2(hv2[2*t + 1], tv.zw, pb);
          }
          float pr = (pa.x + pa.y) + (pb.x + pb.y);
          pr += __shfl_xor(pr, 32);
          if (h == 0) obk[u * 32 + i] = pr;
        }
      }
    }
    __syncthreads();                      // both waves, every phase
  }

  if (wv == 1) {
    // tail: phase 39 data (buffer 1), k = 976..1000
    const float* rx1 = &X1R[1][0][0];
    const float* rx2 = &X2R[1][0][0];
    const int k0 = PLEN * (PHASES - 1) + 1;
    float* Xk = Xp + (size_t)k0 * 128;
    float* obk = ob + (size_t)k0 * 32;
    #pragma unroll 1
    for (int u = 0; u < PLEN; ++u) {
      float x1v = rx1[u * 64 + lane];
      float x2mb = rx2[u * 64 + lane];
      Xk[u * 128 + lane] = x1v;
      Xk[u * 128 + 64 + lane] = x2mb + bl;
      const f32x4* tp = (const f32x4*)(rx2 + u * 64 + h * 32);
      f32x2 pa = {0.f, 0.f}, pb = {0.f, 0.f};
      #pragma unroll
      for (int t = 0; t < 8; ++t) {
        f32x4 tv = tp[t];
        pa = fma2(hv2[2*t],     tv.xy, pa);
        pb = fma2(hv2[2*t + 1], tv.zw, pb);
      }
      float pr = (pa.x + pa.y) + (pb.x + pb.y);
      pr += __shfl_xor(pr, 32);
      if (h == 0) obk[u * 32 + i] = pr;
    }
  }
}

extern "C" void kernel_launch(void* const* d_in, const int* in_sizes, int n_in,
                              void* d_out, int out_size, void* d_ws, size_t ws_size,
                              hipStream_t stream) {
  (void)in_sizes; (void)n_in; (void)out_size; (void)d_ws; (void)ws_size;
  const float* q = (const float*)d_in[0];
  const float* b = (const float*)d_in[1];
  const float* P = (const float*)d_in[2];
  const float* H = (const float*)d_in[3];
  float* Xs = (float*)d_out;
  float* out2 = Xs + (size_t)BATCH * (ITERS + 1) * 128;

  fused_kernel<<<BATCH, 128, 0, stream>>>(q, b, P, H, Xs, out2);
}